// Round 19
// baseline (125.759 us; speedup 1.0000x reference)
//
#include <hip/hip_runtime.h>
#include <hip/hip_bf16.h>

typedef __attribute__((ext_vector_type(8))) short short8;
typedef __attribute__((ext_vector_type(8))) float f32x8;
typedef __attribute__((ext_vector_type(4))) float f32x4;
typedef __attribute__((ext_vector_type(16))) float f32x16;
typedef __attribute__((ext_vector_type(4))) unsigned int u32x4;
typedef unsigned short u16;
typedef unsigned int u32;

#define BQ 8
#define LL 2048
#define NN 1024
#define HH 64
#define BL (BQ * LL) /* 16384 */
#define PART64 4224   /* floats per attn partial: 64 m + 64 l + 64x64 O */
#define NPAIR (8 * 24) /* split-tile pairs */
#define QSCALE 0.0450842213f  /* (1/32) * log2(e): exp2-domain softmax */

static __device__ __forceinline__ u16 f2bf(float f) {
  union { float f; unsigned int u; } cv;
  cv.f = f;
  unsigned int u = cv.u;
  unsigned int rounded = u + 0x7FFFu + ((u >> 16) & 1u);  // RNE
  return (u16)(rounded >> 16);
}

static __device__ __forceinline__ float exp2x(float x) {
  return __builtin_amdgcn_exp2f(x);
}

// pack two f32 -> one dword of 2 bf16 (lo = first arg)
static __device__ __forceinline__ u32 cvtpk(float lo, float hi) {
  u32 d;
  asm("v_cvt_pk_bf16_f32 %0, %1, %2" : "=v"(d) : "v"(lo), "v"(hi));
  return d;
}

// pack 8 f32 -> 8 bf16 by truncation (1 v_perm per 2 elements)
static __device__ __forceinline__ short8 pack_bf16(f32x8 v) {
  short8 o;
  u32* op = (u32*)&o;
#pragma unroll
  for (int w = 0; w < 4; ++w) {
    op[w] = __builtin_amdgcn_perm(__float_as_uint(v[2 * w + 1]),
                                  __float_as_uint(v[2 * w]), 0x07060302u);
  }
  return o;
}

// async global -> LDS, 16B per lane; lds dest must be wave-uniform base
static __device__ __forceinline__ void gload_lds16(const u16* g, u16* l) {
  __builtin_amdgcn_global_load_lds(
      (const __attribute__((address_space(1))) unsigned int*)g,
      (__attribute__((address_space(3))) unsigned int*)l, 16, 0, 0);
}

static __device__ __forceinline__ f32x16 mfma32(short8 a, short8 b, f32x16 c) {
  return __builtin_amdgcn_mfma_f32_32x32x16_bf16(a, b, c, 0, 0, 0);
}

// ---------------------------------------------------------------------------
// Kernel 0: pack W into MFMA B-fragment order (unchanged).
// ---------------------------------------------------------------------------
__global__ __launch_bounds__(256) void wtp_pack(const float* __restrict__ Wq,
                                                const float* __restrict__ Wk,
                                                const float* __restrict__ Wv,
                                                u16* __restrict__ wtp) {
  int gid = blockIdx.x * 256 + threadIdx.x;   // [0, 384*64)
  int f = gid >> 6;
  int l = gid & 63;
  int m = f >> 7;
  int rem = f & 127;
  int nf = rem >> 5;
  int ks = rem & 31;
  int r = l & 15;
  int g = l >> 4;
  const float* src = (m == 0) ? Wq : (m == 1) ? Wk : Wv;
  short8 o;
#pragma unroll
  for (int j = 0; j < 8; ++j)
    o[j] = (short)f2bf(src[(ks * 32 + 8 * g + j) * HH + nf * 16 + r]);
  *(short8*)&wtp[f * 512 + l * 8] = o;
}

// ---------------------------------------------------------------------------
// Kernel 1: qkv projection — EXACT round-12 version (best measured total):
// 64-row blocks, W via global_load_lds, 2-deep x register prefetch.
// ---------------------------------------------------------------------------
__global__ __launch_bounds__(512, 4) void qkv_proj(const float* __restrict__ x,
                                                   const u16* __restrict__ wtp,
                                                   u16* __restrict__ qs,
                                                   u16* __restrict__ ks_,
                                                   u16* __restrict__ vsT) {
  __shared__ u16 xs[2][64 * 72];     // x tile, row stride 72
  __shared__ u16 ws[2][24 * 512];    // W frags: c = F*2 + ks, frag-linear

  const int row0 = blockIdx.x * 64;
  const int tid = threadIdx.x;
  const int wv = tid >> 6;
  const int lane = tid & 63;
  const int r = lane & 15;
  const int g = lane >> 4;
  const int ms = wv >> 2;            // 32-row half
  const int fq = wv & 3;             // 3-F quarter

  const int srow = tid >> 3;         // 0..63
  const int scol = (tid & 7) * 8;    // 0..56
  const float* xsrc = x + (row0 + srow) * NN + scol;

  f32x4 acc[2][3] = {};

  // ---- prologue: chunk 0 to LDS; chunk 1 into regs
  f32x8 xra;
  {
    f32x8 xv = *(const f32x8*)xsrc;
    *(short8*)&xs[0][srow * 72 + scol] = pack_bf16(xv);
#pragma unroll
    for (int j = 0; j < 3; ++j) {
      int c = wv * 3 + j;
      int F = c >> 1, ks = c & 1;
      int gf = F * 32 + ks;
      gload_lds16(wtp + gf * 512 + lane * 8, &ws[0][c * 512]);
    }
    xra = *(const f32x8*)(xsrc + 64);
  }
  __syncthreads();

  int cur = 0;
  for (int kc = 0; kc < 16; ++kc) {
    f32x8 xrb;
    if (kc < 14) xrb = *(const f32x8*)(xsrc + (kc + 2) * 64);
    if (kc < 15) {
#pragma unroll
      for (int j = 0; j < 3; ++j) {
        int c = wv * 3 + j;
        int F = c >> 1, ks = c & 1;
        int gf = F * 32 + (kc + 1) * 2 + ks;
        gload_lds16(wtp + gf * 512 + lane * 8, &ws[cur ^ 1][c * 512]);
      }
    }
#pragma unroll
    for (int ks = 0; ks < 2; ++ks) {
      short8 a[2];
#pragma unroll
      for (int mf = 0; mf < 2; ++mf)
        a[mf] = *(const short8*)&xs[cur][(ms * 32 + mf * 16 + r) * 72 + ks * 32 + 8 * g];
#pragma unroll
      for (int i = 0; i < 3; ++i) {
        int c = (fq * 3 + i) * 2 + ks;
        short8 bfr = *(const short8*)&ws[cur][c * 512 + lane * 8];
#pragma unroll
        for (int mf = 0; mf < 2; ++mf)
          acc[mf][i] = __builtin_amdgcn_mfma_f32_16x16x32_bf16(a[mf], bfr, acc[mf][i], 0, 0, 0);
      }
    }
    if (kc < 15) {
      *(short8*)&xs[cur ^ 1][srow * 72 + scol] = pack_bf16(xra);
      xra = xrb;
    }
    __syncthreads();
    cur ^= 1;
  }

  const int b = row0 >> 11;
  const int kvloc = row0 & (LL - 1);
  u16* vt = xs[0];
#pragma unroll
  for (int mf = 0; mf < 2; ++mf) {
#pragma unroll
    for (int i = 0; i < 3; ++i) {
      const int F = fq * 3 + i, m = F >> 2, nf = F & 3;
      const int rowb = row0 + ms * 32 + mf * 16;
      if (m == 0) {
#pragma unroll
        for (int rr = 0; rr < 4; ++rr)
          qs[(rowb + 4 * g + rr) * HH + nf * 16 + r] = f2bf(acc[mf][i][rr] * QSCALE);
      } else if (m == 1) {
#pragma unroll
        for (int rr = 0; rr < 4; ++rr)
          ks_[(rowb + 4 * g + rr) * HH + nf * 16 + r] = f2bf(acc[mf][i][rr]);
      } else {
#pragma unroll
        for (int rr = 0; rr < 4; ++rr)
          vt[(nf * 16 + r) * 72 + ms * 32 + mf * 16 + 4 * g + rr] = f2bf(acc[mf][i][rr]);
      }
    }
  }
  __syncthreads();
  if (tid < 256) {
    const int h = tid >> 2;
    const int seg = (tid & 3) * 16;
    const u16* s = &vt[h * 72 + seg];
    u16* d = &vsT[(b * HH + h) * LL + kvloc + seg];
    *(short8*)d = *(short8*)s;
    *(short8*)(d + 8) = *(short8*)(s + 8);
  }
}

// ---------------------------------------------------------------------------
// Kernel 2: causal flash attention — EXACT round-12 math/structure, plus
// FUSED MERGE: split-chunk blocks write partials, fence, atomicAdd a
// per-pair counter; the second-arriving block performs the merge (removes
// the attn_merge launch). Counters zeroed per call via hipMemsetAsync.
// ---------------------------------------------------------------------------
__global__ __launch_bounds__(256, 2) void attn(const u16* __restrict__ qs,
                                               const u16* __restrict__ ks,
                                               const u16* __restrict__ vsT,
                                               float* __restrict__ out,
                                               float* __restrict__ part,
                                               u32* __restrict__ cnt) {
  __shared__ float oM[4][64 * 65];
  __shared__ float ml[4][2][64];
  __shared__ int who;

  const int bi = blockIdx.x;
  const int cid = bi >> 3;
  const int b = bi & 7;                // batch -> XCD pinning
  int qt, t0, t1, chunk;
  if (cid < 48) {                      // qt64 8..31: 2 chunks each
    qt = 31 - (cid >> 1);
    chunk = cid & 1;
    const int tmid = qt + 1;
    t0 = chunk ? tmid : 0;
    t1 = chunk ? (2 * qt + 2) : tmid;
  } else {                             // qt64 0..7: single
    qt = 55 - cid; chunk = -1; t0 = 0; t1 = 2 * qt + 2;
  }
  const int q0 = qt * 64;

  const int tid = threadIdx.x;
  const int lane = tid & 63;
  const int wv = tid >> 6;
  const int l31 = lane & 31;
  const int hi = lane >> 5;

  const u16* qp0 = &qs[(size_t)(b * LL + q0 + l31) * HH + 8 * hi];
  const u16* qp1 = qp0 + 32 * HH;
  const short8 qA0 = *(const short8*)(qp0);
  const short8 qA1 = *(const short8*)(qp0 + 16);
  const short8 qA2 = *(const short8*)(qp0 + 32);
  const short8 qA3 = *(const short8*)(qp0 + 48);
  const short8 qB0 = *(const short8*)(qp1);
  const short8 qB1 = *(const short8*)(qp1 + 16);
  const short8 qB2 = *(const short8*)(qp1 + 32);
  const short8 qB3 = *(const short8*)(qp1 + 48);

  float m0 = -1e30f, l0 = 0.0f;        // sub0 state: q-row q0+l31
  float m1 = -1e30f, l1 = 0.0f;        // sub1 state: q-row q0+32+l31
  f32x16 ot00 = {}, ot01 = {}, ot10 = {}, ot11 = {};  // [sub][hb]

  const u16* kbase = &ks[(size_t)(b * LL) * HH + 8 * hi];
  const u16* vb0 = &vsT[(size_t)(b * HH + l31) * LL + 8 * hi];
  const u16* vb1 = vb0 + 32 * LL;

  for (int t = t0 + wv; t < t1; t += 4) {
    const int kv0 = t << 5;
    // ---- K A-frags (shared by both q-subtiles)
    const u16* kp = kbase + (size_t)(kv0 + l31) * HH;
    short8 ka0 = *(const short8*)(kp);
    short8 ka1 = *(const short8*)(kp + 16);
    short8 ka2 = *(const short8*)(kp + 32);
    short8 ka3 = *(const short8*)(kp + 48);
    f32x16 sA = {}, sB = {};
    __builtin_amdgcn_s_setprio(1);
    sA = mfma32(ka0, qA0, sA);
    sA = mfma32(ka1, qA1, sA);
    sA = mfma32(ka2, qA2, sA);
    sA = mfma32(ka3, qA3, sA);
    sB = mfma32(ka0, qB0, sB);
    sB = mfma32(ka1, qB1, sB);
    sB = mfma32(ka2, qB2, sB);
    sB = mfma32(ka3, qB3, sB);
    __builtin_amdgcn_s_setprio(0);
    // ---- V^T A-frags (issue under softmax)
    short8 va00 = *(const short8*)(vb0 + kv0);
    short8 va01 = *(const short8*)(vb0 + kv0 + 16);
    short8 va10 = *(const short8*)(vb1 + kv0);
    short8 va11 = *(const short8*)(vb1 + kv0 + 16);
    // ---- causal masks (kv = kv0 + (e&3)+8*(e>>2)+4*hi; row = q0+32s+l31)
    if (kv0 + 31 > q0) {
      const int thr0 = q0 + l31 - kv0 - 4 * hi;
#pragma unroll
      for (int e = 0; e < 16; ++e)
        if (((e & 3) + 8 * (e >> 2)) > thr0) sA[e] = -1e30f;
    }
    if (kv0 + 31 > q0 + 32) {
      const int thr1 = q0 + 32 + l31 - kv0 - 4 * hi;
#pragma unroll
      for (int e = 0; e < 16; ++e)
        if (((e & 3) + 8 * (e >> 2)) > thr1) sB[e] = -1e30f;
    }
    // ---- softmax sub0
    float pm0 = sA[0];
#pragma unroll
    for (int e = 1; e < 16; ++e) pm0 = fmaxf(pm0, sA[e]);
    pm0 = fmaxf(pm0, __shfl_xor(pm0, 32));
    const float nm0 = fmaxf(fmaxf(m0, pm0), -1e20f);
    const float al0 = exp2x(m0 - nm0);
    float rs0 = 0.0f;
#pragma unroll
    for (int e = 0; e < 16; ++e) {
      float p = exp2x(sA[e] - nm0);
      sA[e] = p;
      rs0 += p;
    }
    rs0 += __shfl_xor(rs0, 32);
    l0 = l0 * al0 + rs0;
    m0 = nm0;
    // ---- softmax sub1
    float pm1 = sB[0];
#pragma unroll
    for (int e = 1; e < 16; ++e) pm1 = fmaxf(pm1, sB[e]);
    pm1 = fmaxf(pm1, __shfl_xor(pm1, 32));
    const float nm1 = fmaxf(fmaxf(m1, pm1), -1e20f);
    const float al1 = exp2x(m1 - nm1);
    float rs1 = 0.0f;
#pragma unroll
    for (int e = 0; e < 16; ++e) {
      float p = exp2x(sB[e] - nm1);
      sB[e] = p;
      rs1 += p;
    }
    rs1 += __shfl_xor(rs1, 32);
    l1 = l1 * al1 + rs1;
    m1 = nm1;
    // ---- pack P (both subs) -> B-frags via cvt_pk + cross-half exchange
    u32 a0x = cvtpk(sA[0], sA[1]),   a0y = cvtpk(sA[2], sA[3]);
    u32 a1x = cvtpk(sA[4], sA[5]),   a1y = cvtpk(sA[6], sA[7]);
    u32 a2x = cvtpk(sA[8], sA[9]),   a2y = cvtpk(sA[10], sA[11]);
    u32 a3x = cvtpk(sA[12], sA[13]), a3y = cvtpk(sA[14], sA[15]);
    u32 b0x = cvtpk(sB[0], sB[1]),   b0y = cvtpk(sB[2], sB[3]);
    u32 b1x = cvtpk(sB[4], sB[5]),   b1y = cvtpk(sB[6], sB[7]);
    u32 b2x = cvtpk(sB[8], sB[9]),   b2y = cvtpk(sB[10], sB[11]);
    u32 b3x = cvtpk(sB[12], sB[13]), b3y = cvtpk(sB[14], sB[15]);
    u32 xa0x = __shfl_xor(a0x, 32), xa0y = __shfl_xor(a0y, 32);
    u32 xa1x = __shfl_xor(a1x, 32), xa1y = __shfl_xor(a1y, 32);
    u32 xa2x = __shfl_xor(a2x, 32), xa2y = __shfl_xor(a2y, 32);
    u32 xa3x = __shfl_xor(a3x, 32), xa3y = __shfl_xor(a3y, 32);
    u32 xb0x = __shfl_xor(b0x, 32), xb0y = __shfl_xor(b0y, 32);
    u32 xb1x = __shfl_xor(b1x, 32), xb1y = __shfl_xor(b1y, 32);
    u32 xb2x = __shfl_xor(b2x, 32), xb2y = __shfl_xor(b2y, 32);
    u32 xb3x = __shfl_xor(b3x, 32), xb3y = __shfl_xor(b3y, 32);
    u32x4 wA0 = { hi ? xa1x : a0x, hi ? xa1y : a0y,
                  hi ? a1x : xa0x, hi ? a1y : xa0y };
    u32x4 wA1 = { hi ? xa3x : a2x, hi ? xa3y : a2y,
                  hi ? a3x : xa2x, hi ? a3y : xa2y };
    u32x4 wB0 = { hi ? xb1x : b0x, hi ? xb1y : b0y,
                  hi ? b1x : xb0x, hi ? b1y : xb0y };
    u32x4 wB1 = { hi ? xb3x : b2x, hi ? xb3y : b2y,
                  hi ? b3x : xb2x, hi ? b3y : xb2y };
    short8 pbA0 = __builtin_bit_cast(short8, wA0);
    short8 pbA1 = __builtin_bit_cast(short8, wA1);
    short8 pbB0 = __builtin_bit_cast(short8, wB0);
    short8 pbB1 = __builtin_bit_cast(short8, wB1);
    // ---- rescale O^T (in-lane: q-col = 32s + l31) and accumulate PV
#pragma unroll
    for (int e = 0; e < 16; ++e) {
      ot00[e] *= al0; ot01[e] *= al0;
      ot10[e] *= al1; ot11[e] *= al1;
    }
    __builtin_amdgcn_s_setprio(1);
    ot00 = mfma32(va00, pbA0, ot00);
    ot00 = mfma32(va01, pbA1, ot00);
    ot01 = mfma32(va10, pbA0, ot01);
    ot01 = mfma32(va11, pbA1, ot01);
    ot10 = mfma32(va00, pbB0, ot10);
    ot10 = mfma32(va01, pbB1, ot10);
    ot11 = mfma32(va10, pbB0, ot11);
    ot11 = mfma32(va11, pbB1, ot11);
    __builtin_amdgcn_s_setprio(0);
  }

  // ---- per-wave partials to LDS (stride 65: conflict-free)
#pragma unroll
  for (int e = 0; e < 16; ++e) {
    const int h = (e & 3) + 8 * (e >> 2) + 4 * hi;
    oM[wv][l31 * 65 + h] = ot00[e];
    oM[wv][l31 * 65 + 32 + h] = ot01[e];
    oM[wv][(32 + l31) * 65 + h] = ot10[e];
    oM[wv][(32 + l31) * 65 + 32 + h] = ot11[e];
  }
  if (hi == 0) {
    ml[wv][0][l31] = m0;
    ml[wv][1][l31] = l0;
    ml[wv][0][32 + l31] = m1;
    ml[wv][1][32 + l31] = l1;
  }
  __syncthreads();

  // ---- merge 4 waves: thread = (row 0..63, 16 h-cols)
  {
    const int row = tid >> 2;
    const int hq = (tid & 3) * 16;
    float M = ml[0][0][row];
#pragma unroll
    for (int w = 1; w < 4; ++w) M = fmaxf(M, ml[w][0][row]);
    float L = 0.0f;
    float O[16] = {};
#pragma unroll
    for (int w = 0; w < 4; ++w) {
      const float aw = exp2x(ml[w][0][row] - M);
      L += ml[w][1][row] * aw;
#pragma unroll
      for (int j = 0; j < 16; ++j)
        O[j] += oM[w][row * 65 + hq + j] * aw;
    }
    if (chunk < 0) {
      const float inv = 1.0f / L;
      float* op = &out[(size_t)(b * LL + q0 + row) * HH + hq];
#pragma unroll
      for (int j4 = 0; j4 < 4; ++j4) {
        float4 r = { O[4 * j4] * inv, O[4 * j4 + 1] * inv,
                     O[4 * j4 + 2] * inv, O[4 * j4 + 3] * inv };
        *(float4*)(op + 4 * j4) = r;
      }
    } else {
      const int pairIdx = b * 24 + (qt - 8);
      float* pp = part + (size_t)(pairIdx * 2 + chunk) * PART64;
      if (hq == 0) { pp[row] = M; pp[64 + row] = L; }
      float* od = &pp[128 + row * 64 + hq];
#pragma unroll
      for (int j4 = 0; j4 < 4; ++j4) {
        float4 r = { O[4 * j4], O[4 * j4 + 1], O[4 * j4 + 2], O[4 * j4 + 3] };
        *(float4*)(od + 4 * j4) = r;
      }
      // ---- last-arrival merge (replaces the attn_merge kernel)
      __syncthreads();
      __threadfence();
      if (tid == 0) who = (int)atomicAdd(&cnt[pairIdx], 1u);
      __syncthreads();
      if (who == 1) {
        __threadfence();
        const float* p0 = part + (size_t)(pairIdx * 2 + 0) * PART64;
        const float* p1 = part + (size_t)(pairIdx * 2 + 1) * PART64;
        const float mm0 = p0[row], ll0 = p0[64 + row];
        const float mm1 = p1[row], ll1 = p1[64 + row];
        const float MM = fmaxf(mm0, mm1);
        const float aa0 = exp2x(mm0 - MM), aa1 = exp2x(mm1 - MM);
        const float inv = 1.0f / (ll0 * aa0 + ll1 * aa1);
        const float* o0 = &p0[128 + row * 64 + hq];
        const float* o1 = &p1[128 + row * 64 + hq];
        float* op = &out[(size_t)(b * LL + q0 + row) * HH + hq];
#pragma unroll
        for (int j4 = 0; j4 < 4; ++j4) {
          float4 A = *(const float4*)(o0 + 4 * j4);
          float4 B = *(const float4*)(o1 + 4 * j4);
          float4 r = { (A.x * aa0 + B.x * aa1) * inv,
                       (A.y * aa0 + B.y * aa1) * inv,
                       (A.z * aa0 + B.z * aa1) * inv,
                       (A.w * aa0 + B.w * aa1) * inv };
          *(float4*)(op + 4 * j4) = r;
        }
      }
    }
  }
}

extern "C" void kernel_launch(void* const* d_in, const int* in_sizes, int n_in,
                              void* d_out, int out_size, void* d_ws, size_t ws_size,
                              hipStream_t stream) {
  const float* x  = (const float*)d_in[0];
  const float* Wk = (const float*)d_in[1];
  const float* Wq = (const float*)d_in[2];
  const float* Wv = (const float*)d_in[3];

  u16* qs  = (u16*)d_ws;             // [16384][64] bf16
  u16* ks  = qs + BL * HH;           // [16384][64] bf16
  u16* vsT = ks + BL * HH;           // [8][64][2048] bf16 (V transposed)
  u16* wtp = vsT + BL * HH;          // [384][512] bf16 (W in frag order)
  float* part = (float*)(wtp + 384 * 512);  // [NPAIR][2][PART64] f32
  u32* cnt = (u32*)(part + (size_t)NPAIR * 2 * PART64);  // [NPAIR]

  hipMemsetAsync(cnt, 0, NPAIR * sizeof(u32), stream);
  wtp_pack<<<96, 256, 0, stream>>>(Wq, Wk, Wv, wtp);
  qkv_proj<<<BL / 64, 512, 0, stream>>>(x, wtp, qs, ks, vsT);
  attn<<<56 * BQ, 256, 0, stream>>>(qs, ks, vsT, (float*)d_out, part, cnt);
}

// Round 20
// 49.006 us; speedup vs baseline: 2.5662x; 2.5662x over previous
//
#include <hip/hip_runtime.h>
#include <hip/hip_bf16.h>

typedef __attribute__((ext_vector_type(8))) short short8;
typedef __attribute__((ext_vector_type(8))) float f32x8;
typedef __attribute__((ext_vector_type(4))) float f32x4;
typedef __attribute__((ext_vector_type(16))) float f32x16;
typedef __attribute__((ext_vector_type(4))) unsigned int u32x4;
typedef unsigned short u16;
typedef unsigned int u32;

#define BQ 8
#define LL 2048
#define NN 1024
#define HH 64
#define BL (BQ * LL) /* 16384 */
#define PART64 4224   /* floats per attn partial: 64 m + 64 l + 64x64 O */
#define QSCALE 0.0450842213f  /* (1/32) * log2(e): exp2-domain softmax */

static __device__ __forceinline__ u16 f2bf(float f) {
  union { float f; unsigned int u; } cv;
  cv.f = f;
  unsigned int u = cv.u;
  unsigned int rounded = u + 0x7FFFu + ((u >> 16) & 1u);  // RNE
  return (u16)(rounded >> 16);
}

static __device__ __forceinline__ float exp2x(float x) {
  return __builtin_amdgcn_exp2f(x);
}

// pack two f32 -> one dword of 2 bf16 (lo = first arg)
static __device__ __forceinline__ u32 cvtpk(float lo, float hi) {
  u32 d;
  asm("v_cvt_pk_bf16_f32 %0, %1, %2" : "=v"(d) : "v"(lo), "v"(hi));
  return d;
}

// pack 8 f32 -> 8 bf16 by truncation (1 v_perm per 2 elements)
static __device__ __forceinline__ short8 pack_bf16(f32x8 v) {
  short8 o;
  u32* op = (u32*)&o;
#pragma unroll
  for (int w = 0; w < 4; ++w) {
    op[w] = __builtin_amdgcn_perm(__float_as_uint(v[2 * w + 1]),
                                  __float_as_uint(v[2 * w]), 0x07060302u);
  }
  return o;
}

// async global -> LDS, 16B per lane; lds dest must be wave-uniform base
static __device__ __forceinline__ void gload_lds16(const u16* g, u16* l) {
  __builtin_amdgcn_global_load_lds(
      (const __attribute__((address_space(1))) unsigned int*)g,
      (__attribute__((address_space(3))) unsigned int*)l, 16, 0, 0);
}

static __device__ __forceinline__ f32x16 mfma32(short8 a, short8 b, f32x16 c) {
  return __builtin_amdgcn_mfma_f32_32x32x16_bf16(a, b, c, 0, 0, 0);
}

// ---------------------------------------------------------------------------
// Kernel 0: pack W into MFMA B-fragment order.
// ---------------------------------------------------------------------------
__global__ __launch_bounds__(256) void wtp_pack(const float* __restrict__ Wq,
                                                const float* __restrict__ Wk,
                                                const float* __restrict__ Wv,
                                                u16* __restrict__ wtp) {
  int gid = blockIdx.x * 256 + threadIdx.x;   // [0, 384*64)
  int f = gid >> 6;
  int l = gid & 63;
  int m = f >> 7;
  int rem = f & 127;
  int nf = rem >> 5;
  int ks = rem & 31;
  int r = l & 15;
  int g = l >> 4;
  const float* src = (m == 0) ? Wq : (m == 1) ? Wk : Wv;
  short8 o;
#pragma unroll
  for (int j = 0; j < 8; ++j)
    o[j] = (short)f2bf(src[(ks * 32 + 8 * g + j) * HH + nf * 16 + r]);
  *(short8*)&wtp[f * 512 + l * 8] = o;
}

// ---------------------------------------------------------------------------
// Kernel 1: qkv projection, LDS-staged GEMM (round-12 exact): 64-row blocks,
// W via global_load_lds, 2-deep x register prefetch.
// ---------------------------------------------------------------------------
__global__ __launch_bounds__(512, 4) void qkv_proj(const float* __restrict__ x,
                                                   const u16* __restrict__ wtp,
                                                   u16* __restrict__ qs,
                                                   u16* __restrict__ ks_,
                                                   u16* __restrict__ vsT) {
  __shared__ u16 xs[2][64 * 72];     // x tile, row stride 72
  __shared__ u16 ws[2][24 * 512];    // W frags: c = F*2 + ks, frag-linear

  const int row0 = blockIdx.x * 64;
  const int tid = threadIdx.x;
  const int wv = tid >> 6;
  const int lane = tid & 63;
  const int r = lane & 15;
  const int g = lane >> 4;
  const int ms = wv >> 2;            // 32-row half
  const int fq = wv & 3;             // 3-F quarter

  const int srow = tid >> 3;         // 0..63
  const int scol = (tid & 7) * 8;    // 0..56
  const float* xsrc = x + (row0 + srow) * NN + scol;

  f32x4 acc[2][3] = {};

  // ---- prologue: chunk 0 to LDS; chunk 1 into regs
  f32x8 xra;
  {
    f32x8 xv = *(const f32x8*)xsrc;
    *(short8*)&xs[0][srow * 72 + scol] = pack_bf16(xv);
#pragma unroll
    for (int j = 0; j < 3; ++j) {
      int c = wv * 3 + j;
      int F = c >> 1, ks = c & 1;
      int gf = F * 32 + ks;
      gload_lds16(wtp + gf * 512 + lane * 8, &ws[0][c * 512]);
    }
    xra = *(const f32x8*)(xsrc + 64);
  }
  __syncthreads();

  int cur = 0;
  for (int kc = 0; kc < 16; ++kc) {
    f32x8 xrb;
    if (kc < 14) xrb = *(const f32x8*)(xsrc + (kc + 2) * 64);
    if (kc < 15) {
#pragma unroll
      for (int j = 0; j < 3; ++j) {
        int c = wv * 3 + j;
        int F = c >> 1, ks = c & 1;
        int gf = F * 32 + (kc + 1) * 2 + ks;
        gload_lds16(wtp + gf * 512 + lane * 8, &ws[cur ^ 1][c * 512]);
      }
    }
#pragma unroll
    for (int ks = 0; ks < 2; ++ks) {
      short8 a[2];
#pragma unroll
      for (int mf = 0; mf < 2; ++mf)
        a[mf] = *(const short8*)&xs[cur][(ms * 32 + mf * 16 + r) * 72 + ks * 32 + 8 * g];
#pragma unroll
      for (int i = 0; i < 3; ++i) {
        int c = (fq * 3 + i) * 2 + ks;
        short8 bfr = *(const short8*)&ws[cur][c * 512 + lane * 8];
#pragma unroll
        for (int mf = 0; mf < 2; ++mf)
          acc[mf][i] = __builtin_amdgcn_mfma_f32_16x16x32_bf16(a[mf], bfr, acc[mf][i], 0, 0, 0);
      }
    }
    if (kc < 15) {
      *(short8*)&xs[cur ^ 1][srow * 72 + scol] = pack_bf16(xra);
      xra = xrb;
    }
    __syncthreads();
    cur ^= 1;
  }

  const int b = row0 >> 11;
  const int kvloc = row0 & (LL - 1);
  u16* vt = xs[0];
#pragma unroll
  for (int mf = 0; mf < 2; ++mf) {
#pragma unroll
    for (int i = 0; i < 3; ++i) {
      const int F = fq * 3 + i, m = F >> 2, nf = F & 3;
      const int rowb = row0 + ms * 32 + mf * 16;
      if (m == 0) {
#pragma unroll
        for (int rr = 0; rr < 4; ++rr)
          qs[(rowb + 4 * g + rr) * HH + nf * 16 + r] = f2bf(acc[mf][i][rr] * QSCALE);
      } else if (m == 1) {
#pragma unroll
        for (int rr = 0; rr < 4; ++rr)
          ks_[(rowb + 4 * g + rr) * HH + nf * 16 + r] = f2bf(acc[mf][i][rr]);
      } else {
#pragma unroll
        for (int rr = 0; rr < 4; ++rr)
          vt[(nf * 16 + r) * 72 + ms * 32 + mf * 16 + 4 * g + rr] = f2bf(acc[mf][i][rr]);
      }
    }
  }
  __syncthreads();
  if (tid < 256) {
    const int h = tid >> 2;
    const int seg = (tid & 3) * 16;
    const u16* s = &vt[h * 72 + seg];
    u16* d = &vsT[(b * HH + h) * LL + kvloc + seg];
    *(short8*)d = *(short8*)s;
    *(short8*)(d + 8) = *(short8*)(s + 8);
  }
}

// ---------------------------------------------------------------------------
// Kernel 2: causal flash attention (round-12 exact): 64 q-rows/wave x 32
// kv/step, 32x32 swapped MFMA, in-register softmax, K/V loaded at tile top.
// ---------------------------------------------------------------------------
__global__ __launch_bounds__(256, 2) void attn(const u16* __restrict__ qs,
                                               const u16* __restrict__ ks,
                                               const u16* __restrict__ vsT,
                                               float* __restrict__ out,
                                               float* __restrict__ part) {
  __shared__ float oM[4][64 * 65];
  __shared__ float ml[4][2][64];

  const int bi = blockIdx.x;
  const int cid = bi >> 3;
  const int b = bi & 7;                // batch -> XCD pinning
  int qt, t0, t1, chunk;
  if (cid < 48) {                      // qt64 8..31: 2 chunks each
    qt = 31 - (cid >> 1);
    chunk = cid & 1;
    const int tmid = qt + 1;
    t0 = chunk ? tmid : 0;
    t1 = chunk ? (2 * qt + 2) : tmid;
  } else {                             // qt64 0..7: single
    qt = 55 - cid; chunk = -1; t0 = 0; t1 = 2 * qt + 2;
  }
  const int q0 = qt * 64;

  const int tid = threadIdx.x;
  const int lane = tid & 63;
  const int wv = tid >> 6;
  const int l31 = lane & 31;
  const int hi = lane >> 5;

  const u16* qp0 = &qs[(size_t)(b * LL + q0 + l31) * HH + 8 * hi];
  const u16* qp1 = qp0 + 32 * HH;
  const short8 qA0 = *(const short8*)(qp0);
  const short8 qA1 = *(const short8*)(qp0 + 16);
  const short8 qA2 = *(const short8*)(qp0 + 32);
  const short8 qA3 = *(const short8*)(qp0 + 48);
  const short8 qB0 = *(const short8*)(qp1);
  const short8 qB1 = *(const short8*)(qp1 + 16);
  const short8 qB2 = *(const short8*)(qp1 + 32);
  const short8 qB3 = *(const short8*)(qp1 + 48);

  float m0 = -1e30f, l0 = 0.0f;        // sub0 state: q-row q0+l31
  float m1 = -1e30f, l1 = 0.0f;        // sub1 state: q-row q0+32+l31
  f32x16 ot00 = {}, ot01 = {}, ot10 = {}, ot11 = {};  // [sub][hb]

  const u16* kbase = &ks[(size_t)(b * LL) * HH + 8 * hi];
  const u16* vb0 = &vsT[(size_t)(b * HH + l31) * LL + 8 * hi];
  const u16* vb1 = vb0 + 32 * LL;

  for (int t = t0 + wv; t < t1; t += 4) {
    const int kv0 = t << 5;
    // ---- K A-frags (shared by both q-subtiles)
    const u16* kp = kbase + (size_t)(kv0 + l31) * HH;
    short8 ka0 = *(const short8*)(kp);
    short8 ka1 = *(const short8*)(kp + 16);
    short8 ka2 = *(const short8*)(kp + 32);
    short8 ka3 = *(const short8*)(kp + 48);
    f32x16 sA = {}, sB = {};
    __builtin_amdgcn_s_setprio(1);
    sA = mfma32(ka0, qA0, sA);
    sA = mfma32(ka1, qA1, sA);
    sA = mfma32(ka2, qA2, sA);
    sA = mfma32(ka3, qA3, sA);
    sB = mfma32(ka0, qB0, sB);
    sB = mfma32(ka1, qB1, sB);
    sB = mfma32(ka2, qB2, sB);
    sB = mfma32(ka3, qB3, sB);
    __builtin_amdgcn_s_setprio(0);
    // ---- V^T A-frags (issue under softmax)
    short8 va00 = *(const short8*)(vb0 + kv0);
    short8 va01 = *(const short8*)(vb0 + kv0 + 16);
    short8 va10 = *(const short8*)(vb1 + kv0);
    short8 va11 = *(const short8*)(vb1 + kv0 + 16);
    // ---- causal masks (kv = kv0 + (e&3)+8*(e>>2)+4*hi; row = q0+32s+l31)
    if (kv0 + 31 > q0) {
      const int thr0 = q0 + l31 - kv0 - 4 * hi;
#pragma unroll
      for (int e = 0; e < 16; ++e)
        if (((e & 3) + 8 * (e >> 2)) > thr0) sA[e] = -1e30f;
    }
    if (kv0 + 31 > q0 + 32) {
      const int thr1 = q0 + 32 + l31 - kv0 - 4 * hi;
#pragma unroll
      for (int e = 0; e < 16; ++e)
        if (((e & 3) + 8 * (e >> 2)) > thr1) sB[e] = -1e30f;
    }
    // ---- softmax sub0
    float pm0 = sA[0];
#pragma unroll
    for (int e = 1; e < 16; ++e) pm0 = fmaxf(pm0, sA[e]);
    pm0 = fmaxf(pm0, __shfl_xor(pm0, 32));
    const float nm0 = fmaxf(fmaxf(m0, pm0), -1e20f);
    const float al0 = exp2x(m0 - nm0);
    float rs0 = 0.0f;
#pragma unroll
    for (int e = 0; e < 16; ++e) {
      float p = exp2x(sA[e] - nm0);
      sA[e] = p;
      rs0 += p;
    }
    rs0 += __shfl_xor(rs0, 32);
    l0 = l0 * al0 + rs0;
    m0 = nm0;
    // ---- softmax sub1
    float pm1 = sB[0];
#pragma unroll
    for (int e = 1; e < 16; ++e) pm1 = fmaxf(pm1, sB[e]);
    pm1 = fmaxf(pm1, __shfl_xor(pm1, 32));
    const float nm1 = fmaxf(fmaxf(m1, pm1), -1e20f);
    const float al1 = exp2x(m1 - nm1);
    float rs1 = 0.0f;
#pragma unroll
    for (int e = 0; e < 16; ++e) {
      float p = exp2x(sB[e] - nm1);
      sB[e] = p;
      rs1 += p;
    }
    rs1 += __shfl_xor(rs1, 32);
    l1 = l1 * al1 + rs1;
    m1 = nm1;
    // ---- pack P (both subs) -> B-frags via cvt_pk + cross-half exchange
    u32 a0x = cvtpk(sA[0], sA[1]),   a0y = cvtpk(sA[2], sA[3]);
    u32 a1x = cvtpk(sA[4], sA[5]),   a1y = cvtpk(sA[6], sA[7]);
    u32 a2x = cvtpk(sA[8], sA[9]),   a2y = cvtpk(sA[10], sA[11]);
    u32 a3x = cvtpk(sA[12], sA[13]), a3y = cvtpk(sA[14], sA[15]);
    u32 b0x = cvtpk(sB[0], sB[1]),   b0y = cvtpk(sB[2], sB[3]);
    u32 b1x = cvtpk(sB[4], sB[5]),   b1y = cvtpk(sB[6], sB[7]);
    u32 b2x = cvtpk(sB[8], sB[9]),   b2y = cvtpk(sB[10], sB[11]);
    u32 b3x = cvtpk(sB[12], sB[13]), b3y = cvtpk(sB[14], sB[15]);
    u32 xa0x = __shfl_xor(a0x, 32), xa0y = __shfl_xor(a0y, 32);
    u32 xa1x = __shfl_xor(a1x, 32), xa1y = __shfl_xor(a1y, 32);
    u32 xa2x = __shfl_xor(a2x, 32), xa2y = __shfl_xor(a2y, 32);
    u32 xa3x = __shfl_xor(a3x, 32), xa3y = __shfl_xor(a3y, 32);
    u32 xb0x = __shfl_xor(b0x, 32), xb0y = __shfl_xor(b0y, 32);
    u32 xb1x = __shfl_xor(b1x, 32), xb1y = __shfl_xor(b1y, 32);
    u32 xb2x = __shfl_xor(b2x, 32), xb2y = __shfl_xor(b2y, 32);
    u32 xb3x = __shfl_xor(b3x, 32), xb3y = __shfl_xor(b3y, 32);
    u32x4 wA0 = { hi ? xa1x : a0x, hi ? xa1y : a0y,
                  hi ? a1x : xa0x, hi ? a1y : xa0y };
    u32x4 wA1 = { hi ? xa3x : a2x, hi ? xa3y : a2y,
                  hi ? a3x : xa2x, hi ? a3y : xa2y };
    u32x4 wB0 = { hi ? xb1x : b0x, hi ? xb1y : b0y,
                  hi ? b1x : xb0x, hi ? b1y : xb0y };
    u32x4 wB1 = { hi ? xb3x : b2x, hi ? xb3y : b2y,
                  hi ? b3x : xb2x, hi ? b3y : xb2y };
    short8 pbA0 = __builtin_bit_cast(short8, wA0);
    short8 pbA1 = __builtin_bit_cast(short8, wA1);
    short8 pbB0 = __builtin_bit_cast(short8, wB0);
    short8 pbB1 = __builtin_bit_cast(short8, wB1);
    // ---- rescale O^T (in-lane: q-col = 32s + l31) and accumulate PV
#pragma unroll
    for (int e = 0; e < 16; ++e) {
      ot00[e] *= al0; ot01[e] *= al0;
      ot10[e] *= al1; ot11[e] *= al1;
    }
    __builtin_amdgcn_s_setprio(1);
    ot00 = mfma32(va00, pbA0, ot00);
    ot00 = mfma32(va01, pbA1, ot00);
    ot01 = mfma32(va10, pbA0, ot01);
    ot01 = mfma32(va11, pbA1, ot01);
    ot10 = mfma32(va00, pbB0, ot10);
    ot10 = mfma32(va01, pbB1, ot10);
    ot11 = mfma32(va10, pbB0, ot11);
    ot11 = mfma32(va11, pbB1, ot11);
    __builtin_amdgcn_s_setprio(0);
  }

  // ---- per-wave partials to LDS (stride 65: conflict-free)
#pragma unroll
  for (int e = 0; e < 16; ++e) {
    const int h = (e & 3) + 8 * (e >> 2) + 4 * hi;
    oM[wv][l31 * 65 + h] = ot00[e];
    oM[wv][l31 * 65 + 32 + h] = ot01[e];
    oM[wv][(32 + l31) * 65 + h] = ot10[e];
    oM[wv][(32 + l31) * 65 + 32 + h] = ot11[e];
  }
  if (hi == 0) {
    ml[wv][0][l31] = m0;
    ml[wv][1][l31] = l0;
    ml[wv][0][32 + l31] = m1;
    ml[wv][1][32 + l31] = l1;
  }
  __syncthreads();

  // ---- merge 4 waves: thread = (row 0..63, 16 h-cols)
  {
    const int row = tid >> 2;
    const int hq = (tid & 3) * 16;
    float M = ml[0][0][row];
#pragma unroll
    for (int w = 1; w < 4; ++w) M = fmaxf(M, ml[w][0][row]);
    float L = 0.0f;
    float O[16] = {};
#pragma unroll
    for (int w = 0; w < 4; ++w) {
      const float aw = exp2x(ml[w][0][row] - M);
      L += ml[w][1][row] * aw;
#pragma unroll
      for (int j = 0; j < 16; ++j)
        O[j] += oM[w][row * 65 + hq + j] * aw;
    }
    if (chunk < 0) {
      const float inv = 1.0f / L;
      float* op = &out[(size_t)(b * LL + q0 + row) * HH + hq];
#pragma unroll
      for (int j4 = 0; j4 < 4; ++j4) {
        float4 r = { O[4 * j4] * inv, O[4 * j4 + 1] * inv,
                     O[4 * j4 + 2] * inv, O[4 * j4 + 3] * inv };
        *(float4*)(op + 4 * j4) = r;
      }
    } else {
      float* pp = part + (size_t)((b * 24 + (qt - 8)) * 2 + chunk) * PART64;
      if (hq == 0) { pp[row] = M; pp[64 + row] = L; }
      float* od = &pp[128 + row * 64 + hq];
#pragma unroll
      for (int j4 = 0; j4 < 4; ++j4) {
        float4 r = { O[4 * j4], O[4 * j4 + 1], O[4 * j4 + 2], O[4 * j4 + 3] };
        *(float4*)(od + 4 * j4) = r;
      }
    }
  }
}

// ---------------------------------------------------------------------------
// Kernel 3: merge the 2 kv-chunk partials for q-tiles 8..31 (64-row tiles).
// ---------------------------------------------------------------------------
__global__ __launch_bounds__(256) void attn_merge(const float* __restrict__ part,
                                                  float* __restrict__ out) {
  const int bi = blockIdx.x;           // [0, 192) = b*24 + qi
  const int b = bi / 24;
  const int qi = bi % 24;              // qt64 = 8 + qi
  const float* p0 = part + (size_t)((b * 24 + qi) * 2 + 0) * PART64;
  const float* p1 = part + (size_t)((b * 24 + qi) * 2 + 1) * PART64;
  const int row = threadIdx.x >> 2;    // 0..63
  const int hq = (threadIdx.x & 3) * 16;
  const float m0 = p0[row], l0 = p0[64 + row];
  const float m1 = p1[row], l1 = p1[64 + row];
  const float M = fmaxf(m0, m1);
  const float a0 = exp2x(m0 - M), a1 = exp2x(m1 - M);
  const float inv = 1.0f / (l0 * a0 + l1 * a1);
  const float* o0 = &p0[128 + row * 64 + hq];
  const float* o1 = &p1[128 + row * 64 + hq];
  float* op = &out[(size_t)(b * LL + (8 + qi) * 64 + row) * HH + hq];
#pragma unroll
  for (int j4 = 0; j4 < 4; ++j4) {
    float4 A = *(const float4*)(o0 + 4 * j4);
    float4 B = *(const float4*)(o1 + 4 * j4);
    float4 r = { (A.x * a0 + B.x * a1) * inv, (A.y * a0 + B.y * a1) * inv,
                 (A.z * a0 + B.z * a1) * inv, (A.w * a0 + B.w * a1) * inv };
    *(float4*)(op + 4 * j4) = r;
  }
}

extern "C" void kernel_launch(void* const* d_in, const int* in_sizes, int n_in,
                              void* d_out, int out_size, void* d_ws, size_t ws_size,
                              hipStream_t stream) {
  const float* x  = (const float*)d_in[0];
  const float* Wk = (const float*)d_in[1];
  const float* Wq = (const float*)d_in[2];
  const float* Wv = (const float*)d_in[3];

  u16* qs  = (u16*)d_ws;             // [16384][64] bf16
  u16* ks  = qs + BL * HH;           // [16384][64] bf16
  u16* vsT = ks + BL * HH;           // [8][64][2048] bf16 (V transposed)
  u16* wtp = vsT + BL * HH;          // [384][512] bf16 (W in frag order)
  float* part = (float*)(wtp + 384 * 512);  // [8*24][2][PART64] f32

  wtp_pack<<<96, 256, 0, stream>>>(Wq, Wk, Wv, wtp);
  qkv_proj<<<BL / 64, 512, 0, stream>>>(x, wtp, qs, ks, vsT);
  attn<<<56 * BQ, 256, 0, stream>>>(qs, ks, vsT, (float*)d_out, part);
  attn_merge<<<192, 256, 0, stream>>>(part, (float*)d_out);
}